// Round 17
// baseline (425.211 us; speedup 1.0000x reference)
//
#include <hip/hip_runtime.h>
#include <hip/hip_bf16.h>

#define CB 64      // B == C == 64
#define HH 128
#define WW 128
#define KK 4
#define EPSV 1e-5f
#define HWSZ (HH*WW)

using f32x4   = __attribute__((ext_vector_type(4))) float;
using f32x16  = __attribute__((ext_vector_type(16))) float;
using short8  = __attribute__((ext_vector_type(8))) short;

// ---- workspace layout ----
static constexpr size_t WS_POOLED = 0;          // [64][128] (unused after fusion; kept)
static constexpr size_t WS_HID    = 8192;       // [64][64]
static constexpr size_t WS_KERN   = 12288;      // [64][2304] byte range reused by bf16 weights
static constexpr size_t WS_SSQ    = 159744;     // [64][4] (unused after fusion; kept)
static constexpr size_t WS_WK     = 160000;     // [64][576]
static constexpr size_t WS_EFFW   = 196864;     // [64][576]
static constexpr size_t WS_FUW2   = 233728;     // [64][64]
static constexpr size_t WS_FDINV  = 237824;     // [64]
static constexpr size_t WS_FDBETA = 237888;     // [64]
static constexpr size_t WS_FUINV  = 237952;     // [64]
static constexpr size_t WS_FUBETA = 238016;     // [64]
// byte offsets inside dead WS_KERN byte range (49152..638976):
// lane-coalesced weight layout: [tap][Kq][oh][lane 0..63][8 bf16]
static constexpr size_t WT3_BYTE = 49152;              // bf16 36864 = 73728 B
static constexpr size_t WFD_BYTE = 49152 + 73728;      // bf16 36864
static constexpr size_t W1_BYTE  = 49152 + 147456;     // bf16 [Kq][oh][lane][8] = 4096
// big buffers:
static constexpr size_t WS_PART_BYTE   = 4u << 20;     // f32 [64][64 ypairs][128]
static constexpr size_t WS_DEPTHT_BYTE = 8u << 20;     // bf16 [64][130][130][64] zero-padded
static constexpr size_t WS_RGBT_BYTE   = 140u << 20;   // bf16 [64][130][130][64] zero-padded

// ---------------- small kernels ----------------

__global__ void k_consts(const float* __restrict__ fd_scale, const float* __restrict__ fd_bias,
                         const float* __restrict__ fd_mean, const float* __restrict__ fd_var,
                         const float* __restrict__ fd_b,
                         const float* __restrict__ fu_scale, const float* __restrict__ fu_bias,
                         const float* __restrict__ fu_mean, const float* __restrict__ fu_var,
                         const float* __restrict__ fu_b,
                         float* __restrict__ ws) {
    int c = threadIdx.x;
    if (c < CB) {
        float fdi = fd_scale[c] / sqrtf(fd_var[c] + EPSV);
        ws[WS_FDINV + c]  = fdi;
        ws[WS_FDBETA + c] = (fd_b[c] - fd_mean[c]) * fdi + fd_bias[c];
        float fui = fu_scale[c] / sqrtf(fu_var[c] + EPSV);
        ws[WS_FUINV + c]  = fui;
        ws[WS_FUBETA + c] = (fu_b[c] - fu_mean[c]) * fui + fu_bias[c];
    }
}

__device__ __forceinline__ unsigned int pack_bf16(float a, float b) {
    __hip_bfloat16 ha = __float2bfloat16(a), hb = __float2bfloat16(b);
    return (unsigned int)*(unsigned short*)&ha | ((unsigned int)*(unsigned short*)&hb << 16);
}

// NCHW f32 -> padded NHWC bf16 transpose + pool partials (round-13, verified ~175 us).
__global__ __launch_bounds__(256) void k_nhwc(const float* __restrict__ rgb,
                                              const float* __restrict__ depth,
                                              unsigned int* __restrict__ rgbT,
                                              unsigned int* __restrict__ depthT,
                                              float* __restrict__ part) {
    int g = blockIdx.x;    // 0..63 row-pairs; 64 = border-rows block
    int b = blockIdx.y;
    int t = threadIdx.x;

    if (g == 64) {         // zero padded rows yp=0,129 for both tensors
        unsigned int* dR0 = rgbT   + ((size_t)b * 130 + 0)   * 130 * 32;
        unsigned int* dR1 = rgbT   + ((size_t)b * 130 + 129) * 130 * 32;
        unsigned int* dD0 = depthT + ((size_t)b * 130 + 0)   * 130 * 32;
        unsigned int* dD1 = depthT + ((size_t)b * 130 + 129) * 130 * 32;
        for (int i = t; i < 130 * 32; i += 256) {
            dR0[i] = 0u; dR1[i] = 0u; dD0[i] = 0u; dD1[i] = 0u;
        }
        return;
    }
    int y0 = g * 2;
    {   // side borders x'=0,129 for padded rows y0+1, y0+2 (both tensors)
        int tensor = t >> 7, side = (t >> 6) & 1, row = (t >> 5) & 1, j = t & 31;
        unsigned int* d = tensor ? depthT : rgbT;
        d[(((size_t)b * 130 + (y0 + 1 + row)) * 130 + (side ? 129 : 0)) * 32 + j] = 0u;
    }

    __shared__ unsigned int staged[32][260];   // [ch-pair][px 0..255], padded
    __shared__ float poolacc[128];
    int w = t >> 6, lane = t & 63;

    #pragma unroll
    for (int ph = 0; ph < 2; ++ph) {
        const float* src = ph ? depth : rgb;
        unsigned int* dst = ph ? depthT : rgbT;
        if (ph) __syncthreads();            // staged reuse barrier

        #pragma unroll
        for (int i = 0; i < 8; ++i) {
            int pair = i * 4 + w;           // wave-uniform
            int c = pair * 2;
            const float4* s0 = (const float4*)(src + ((size_t)(b * CB + c)) * HWSZ
                                               + (size_t)y0 * WW);
            const float4* s1 = (const float4*)(src + ((size_t)(b * CB + c + 1)) * HWSZ
                                               + (size_t)y0 * WW);
            float4 v0 = s0[lane];
            float4 v1 = s1[lane];
            unsigned int pk0 = pack_bf16(v0.x, v1.x);
            unsigned int pk1 = pack_bf16(v0.y, v1.y);
            unsigned int pk2 = pack_bf16(v0.z, v1.z);
            unsigned int pk3 = pack_bf16(v0.w, v1.w);
            uint4 q = {pk0, pk1, pk2, pk3};
            *(uint4*)&staged[pair][lane * 4] = q;
            float sa = v0.x + v0.y + v0.z + v0.w;
            float sb = v1.x + v1.y + v1.z + v1.w;
            #pragma unroll
            for (int off = 32; off; off >>= 1) {
                sa += __shfl_down(sa, off, 64);
                sb += __shfl_down(sb, off, 64);
            }
            if (lane == 0) {
                poolacc[ph * 64 + c]     = sa;
                poolacc[ph * 64 + c + 1] = sb;
            }
        }
        __syncthreads();

        {   // write: thread t -> pixel t, FULL 128B NHWC line
            int row = t >> 7, x = t & 127;
            unsigned int line[32];
            #pragma unroll
            for (int p = 0; p < 32; ++p) line[p] = staged[p][t];
            unsigned int* dp = dst + (((size_t)b * 130 + (y0 + 1 + row)) * 130 + 1 + x) * 32;
            #pragma unroll
            for (int q = 0; q < 8; ++q)
                *(uint4*)(dp + q * 4) = *(uint4*)&line[q * 4];
        }
    }
    __syncthreads();
    if (t < 128)
        part[((size_t)b * 64 + g) * 128 + t] = poolacc[t];
}

// fused pool-finish + hidden MLP (one launch, pooled stays in LDS)
__global__ __launch_bounds__(256) void k_poolhid(const float* __restrict__ part,
                                                 const float* __restrict__ w1,
                                                 const float* __restrict__ b1,
                                                 float* __restrict__ ws) {
    int b = blockIdx.x, t = threadIdx.x, cc = t & 127, q = t >> 7;
    float s = 0.f;
    for (int g = q * 32; g < q * 32 + 32; ++g)
        s += part[((size_t)b * 64 + g) * 128 + cc];
    __shared__ float red[2][128];
    __shared__ float p[128];
    red[q][cc] = s;
    __syncthreads();
    if (t < 128) p[t] = (red[0][t] + red[1][t]) * (1.f / 16384.f);
    __syncthreads();
    if (t < CB) {
        float s2 = b1[t];
        const float* wr = w1 + t * 128;
        #pragma unroll 8
        for (int i = 0; i < 128; ++i) s2 += p[i] * wr[i];
        ws[WS_HID + b * CB + t] = fmaxf(s2, 0.f);
    }
}

// fused kernel-gen + softmax + weighted-kernel (kern rows live in LDS only)
__global__ __launch_bounds__(256) void k_kernwk(const float* __restrict__ w2,
                                                const float* __restrict__ b2,
                                                float* __restrict__ ws) {
    __shared__ float h[CB];
    __shared__ float kernL[2304];
    __shared__ float attn[KK];
    __shared__ float ssq[KK];
    int b = blockIdx.x, t = threadIdx.x;
    if (t < CB) h[t] = ws[WS_HID + b * CB + t];
    __syncthreads();
    float local = 0.f;
    #pragma unroll
    for (int r9 = 0; r9 < 9; ++r9) {
        int r = t * 9 + r9;
        float s = b2[r];
        const float* wr = w2 + r * CB;
        #pragma unroll 8
        for (int m = 0; m < CB; ++m) s += h[m] * wr[m];
        kernL[r] = s;
        local += s * s;
    }
    #pragma unroll
    for (int off = 32; off; off >>= 1) local += __shfl_down(local, off, 64);
    if ((t & 63) == 0) ssq[t >> 6] = local;   // wave w covers rows of kernel k=w
    __syncthreads();
    if (t == 0) {
        float n[KK], m = -1e30f;
        #pragma unroll
        for (int k = 0; k < KK; ++k) { n[k] = sqrtf(ssq[k]); m = fmaxf(m, n[k]); }
        float e[KK], den = 0.f;
        #pragma unroll
        for (int k = 0; k < KK; ++k) { e[k] = expf(n[k] - m); den += e[k]; }
        float inv = 1.f / den;
        #pragma unroll
        for (int k = 0; k < KK; ++k) attn[k] = e[k] * inv;
    }
    __syncthreads();
    float a0 = attn[0], a1 = attn[1], a2 = attn[2], a3 = attn[3];
    for (int idx = t; idx < 576; idx += 256) {
        float s = a0 * kernL[idx] + a1 * kernL[576 + idx]
                + a2 * kernL[1152 + idx] + a3 * kernL[1728 + idx];
        ws[WS_WK + b * 576 + idx] = s;
    }
}

__global__ __launch_bounds__(256) void k_effw(const float* __restrict__ fu_w, float* __restrict__ ws) {
    int o = blockIdx.x, t = threadIdx.x;
    __shared__ float fw[CB];
    float fi = ws[WS_FUINV + o];
    if (t < CB) {
        fw[t] = fu_w[o * 128 + t] * fi;
        ws[WS_FUW2 + o * CB + t] = fu_w[o * 128 + CB + t] * fi;
    }
    __syncthreads();
    for (int idx = t; idx < 576; idx += 256) {
        float s = 0.f;
        #pragma unroll 8
        for (int c = 0; c < CB; ++c) s += fw[c] * ws[WS_WK + c * 576 + idx];
        ws[WS_EFFW + o * 576 + idx] = s;
    }
}

// lane-coalesced A-frag layouts for mfma_32x32x16:
//   wt[(((tap*4+Kq)*2+oh)*64 + lane)*8 + j] = W[och = oh*32+(lane&31)][cin = Kq*16+(lane>>5)*8+j]
__global__ void k_prepw(const float* __restrict__ fd_w, float* __restrict__ ws) {
    int e = blockIdx.x * 256 + threadIdx.x;
    unsigned short* wt3 = (unsigned short*)((char*)ws + WT3_BYTE);
    unsigned short* wfd = (unsigned short*)((char*)ws + WFD_BYTE);
    unsigned short* w1o = (unsigned short*)((char*)ws + W1_BYTE);
    if (e < 73728) {
        int set = (e >= 36864) ? 1 : 0;
        int e2 = set ? e - 36864 : e;
        int j = e2 & 7, l = (e2 >> 3) & 63, oh = (e2 >> 9) & 1, Kq = (e2 >> 10) & 3, tap = e2 >> 12;
        int och = oh * 32 + (l & 31);
        int cin = Kq * 16 + (l >> 5) * 8 + j;
        float v = set ? fd_w[(och * 64 + cin) * 9 + tap] * ws[WS_FDINV + och]
                      : ws[WS_EFFW + och * 576 + cin * 9 + tap];
        __hip_bfloat16 h = __float2bfloat16(v);
        (set ? wfd : wt3)[e2] = *(unsigned short*)&h;
    } else if (e < 77824) {
        int e3 = e - 73728;
        int j = e3 & 7, l = (e3 >> 3) & 63, oh = (e3 >> 9) & 1, Kq = e3 >> 10;
        int och = oh * 32 + (l & 31);
        int cin = Kq * 16 + (l >> 5) * 8 + j;
        __hip_bfloat16 h = __float2bfloat16(ws[WS_FUW2 + och * CB + cin]);
        w1o[e3] = *(unsigned short*)&h;
    }
}

// ---------------- fused conv kernel (dedup'd LDS reads) ----------------
// Tile 32x8 px. Input LDS: [10 rows][34 x][8 chunks of 8 bf16] = 43520 B,
// linear dest, XOR swizzle (cs ^ (xx&7)) on global source + ds_read side.
// Wave w owns ALL 64 out-channels for rows {2w, 2w+1}.
// NEW conv loop: dj -> Kq outer; per (dj,Kq) load 4 DISTINCT row-frags r[0..3]
// (rows 2w..2w+3) + 6 weight frags, run 12 MFMAs with r[di+pxg]. LDS reads per
// conv per wave: 72 -> 48 (rows 2w+1/2w+2 were read twice before).
// (256,2): no spill (WRITE = 262144 KB exact).

__device__ __forceinline__ void gload_lds16(const void* g, void* l) {
    __builtin_amdgcn_global_load_lds((const __attribute__((address_space(1))) unsigned int*)g,
                                     (__attribute__((address_space(3))) unsigned int*)l, 16, 0, 0);
}

__device__ __forceinline__ void stage_async(const unsigned short* __restrict__ T, int b,
                                            int y0p, int x0p, int t, char* tile) {
    const char* base = (const char*)(T + (((size_t)b * 130 + y0p) * 130 + x0p) * 64);
    #pragma unroll
    for (int it = 0; it < 10; ++it) {
        int n = it * 256 + t;
        int row = n / 272, rem = n - row * 272;
        int xx = rem >> 3, cs = rem & 7;
        gload_lds16(base + (size_t)row * 16640 + xx * 128 + ((cs ^ (xx & 7)) << 4),
                    tile + n * 16);
    }
    if (t < 160) {
        int n = 2560 + t;
        int row = n / 272, rem = n - row * 272;
        int xx = rem >> 3, cs = rem & 7;
        gload_lds16(base + (size_t)row * 16640 + xx * 128 + ((cs ^ (xx & 7)) << 4),
                    tile + n * 16);
    }
}

__device__ __forceinline__ void conv3x3w2(f32x16 (&acc)[2][2], const unsigned short* __restrict__ Wt,
                                          const char* tile, int w, int lane) {
    int px = lane & 31, hi = lane >> 5;
    #pragma unroll
    for (int dj = 0; dj < 3; ++dj) {
        const int xx = px + dj;
        const char* bbase = tile + xx * 128;
        #pragma unroll
        for (int Kq = 0; Kq < 4; ++Kq) {
            // 6 weight frags for this (dj,Kq): taps di*3+dj
            short8 wa[3][2];
            #pragma unroll
            for (int di = 0; di < 3; ++di)
                #pragma unroll
                for (int oh = 0; oh < 2; ++oh)
                    wa[di][oh] = *(const short8*)(Wt +
                        (((((di * 3 + dj) * 4 + Kq) * 2 + oh) * 64 + lane) << 3));
            // 4 distinct B-frags: rows 2w..2w+3 at (xx, plane Kq*2+hi)
            const int so = ((Kq * 2 + hi) ^ (xx & 7)) << 4;
            short8 r[4];
            #pragma unroll
            for (int j = 0; j < 4; ++j)
                r[j] = *(const short8*)(bbase + (size_t)(w * 2 + j) * 4352 + so);
            __builtin_amdgcn_s_setprio(1);
            #pragma unroll
            for (int di = 0; di < 3; ++di)
                #pragma unroll
                for (int pxg = 0; pxg < 2; ++pxg) {
                    acc[0][pxg] = __builtin_amdgcn_mfma_f32_32x32x16_bf16(wa[di][0], r[di + pxg], acc[0][pxg], 0, 0, 0);
                    acc[1][pxg] = __builtin_amdgcn_mfma_f32_32x32x16_bf16(wa[di][1], r[di + pxg], acc[1][pxg], 0, 0, 0);
                }
            __builtin_amdgcn_s_setprio(0);
        }
    }
}

__global__ __launch_bounds__(256, 2) void k_fused(const unsigned short* __restrict__ rgbT,
                                                  const unsigned short* __restrict__ depthT,
                                                  const float* __restrict__ ws,
                                                  float* __restrict__ out) {
    __shared__ __align__(16) char tile[43520];
    int b = blockIdx.z;
    int x0 = blockIdx.x * 32, y0 = blockIdx.y * 8;
    int t = threadIdx.x, lane = t & 63, w = t >> 6;
    int px = lane & 31, hi = lane >> 5;

    const unsigned short* wfd = (const unsigned short*)((const char*)ws + WFD_BYTE);
    const unsigned short* wt3 = (const unsigned short*)((const char*)ws + WT3_BYTE);
    const unsigned short* w1o = (const unsigned short*)((const char*)ws + W1_BYTE);

    // ---- issue depth tile loads (async into LDS) ----
    stage_async(depthT, b, y0, x0, t, tile);

    // facc init = fd beta (C-layout: och = oh*32 + (r&3) + 8*(r>>2) + 4*hi)
    f32x16 facc[2][2];
    #pragma unroll
    for (int oh = 0; oh < 2; ++oh) {
        f32x16 bi;
        #pragma unroll
        for (int r = 0; r < 16; ++r)
            bi[r] = ws[WS_FDBETA + oh * 32 + (r & 3) + 8 * (r >> 2) + 4 * hi];
        facc[oh][0] = bi;
        facc[oh][1] = bi;
    }
    __syncthreads();   // depth tile resident

    conv3x3w2(facc, wfd, tile, w, lane);
    __syncthreads();   // depth-tile reads done; reuse tile[0..32768) as freq_lds

    // ---- freq -> LDS [px][ch] bf16, chunk-slot XOR by (px&7), ReLU ----
    {
        unsigned int* fl = (unsigned int*)tile;
        #pragma unroll
        for (int oh = 0; oh < 2; ++oh)
            #pragma unroll
            for (int pxg = 0; pxg < 2; ++pxg) {
                int p = (w * 2 + pxg) * 32 + px;
                #pragma unroll
                for (int q = 0; q < 4; ++q) {
                    unsigned int u0 = pack_bf16(fmaxf(facc[oh][pxg][q * 4 + 0], 0.f),
                                                fmaxf(facc[oh][pxg][q * 4 + 1], 0.f));
                    unsigned int u1 = pack_bf16(fmaxf(facc[oh][pxg][q * 4 + 2], 0.f),
                                                fmaxf(facc[oh][pxg][q * 4 + 3], 0.f));
                    int slot = (q + oh * 4) ^ (p & 7);
                    int dw = p * 32 + slot * 4 + hi * 2;
                    fl[dw] = u0;
                    fl[dw + 1] = u1;
                }
            }
    }
    __syncthreads();   // freq_lds visible

    // ---- acc init + 1x1 over freq ----
    f32x16 acc[2][2];
    #pragma unroll
    for (int oh = 0; oh < 2; ++oh) {
        f32x16 bi;
        #pragma unroll
        for (int r = 0; r < 16; ++r)
            bi[r] = ws[WS_FUBETA + oh * 32 + (r & 3) + 8 * (r >> 2) + 4 * hi];
        acc[oh][0] = bi;
        acc[oh][1] = bi;
    }
    #pragma unroll
    for (int Kq = 0; Kq < 4; ++Kq) {
        short8 w1a[2];
        #pragma unroll
        for (int oh = 0; oh < 2; ++oh)
            w1a[oh] = *(const short8*)(w1o + (((Kq * 2 + oh) * 64 + lane) << 3));
        #pragma unroll
        for (int pxg = 0; pxg < 2; ++pxg) {
            int p = (w * 2 + pxg) * 32 + px;
            short8 bf = *(const short8*)(tile + p * 128 + (((Kq * 2 + hi) ^ (p & 7)) << 4));
            __builtin_amdgcn_s_setprio(1);
            acc[0][pxg] = __builtin_amdgcn_mfma_f32_32x32x16_bf16(w1a[0], bf, acc[0][pxg], 0, 0, 0);
            acc[1][pxg] = __builtin_amdgcn_mfma_f32_32x32x16_bf16(w1a[1], bf, acc[1][pxg], 0, 0, 0);
            __builtin_amdgcn_s_setprio(0);
        }
    }
    __syncthreads();   // freq_lds reads done

    // ---- issue rgb tile loads ----
    stage_async(rgbT, b, y0, x0, t, tile);
    __syncthreads();   // rgb tile resident

    conv3x3w2(acc, wt3, tile, w, lane);
    __syncthreads();   // tile reads done; reuse as transpose slab

    // ---- epilogue: per-wave 64x33 slab transpose -> full-128B-line stores ----
    float* slab = (float*)(tile + w * 8704);
    #pragma unroll
    for (int pxg = 0; pxg < 2; ++pxg) {
        #pragma unroll
        for (int oh = 0; oh < 2; ++oh)
            #pragma unroll
            for (int q = 0; q < 4; ++q)
                #pragma unroll
                for (int i = 0; i < 4; ++i)
                    slab[(oh * 32 + q * 8 + hi * 4 + i) * 33 + px] =
                        fmaxf(acc[oh][pxg][q * 4 + i], 0.f);
        int y = y0 + w * 2 + pxg;
        #pragma unroll
        for (int c2 = 0; c2 < 32; ++c2) {
            int c = c2 * 2 + hi;
            out[(size_t)(b * CB + c) * HWSZ + (size_t)y * WW + x0 + px] = slab[c * 33 + px];
        }
    }
}

// ---------------- launch ----------------

extern "C" void kernel_launch(void* const* d_in, const int* in_sizes, int n_in,
                              void* d_out, int out_size, void* d_ws, size_t ws_size,
                              hipStream_t stream) {
    const float* rgb      = (const float*)d_in[0];
    const float* depth    = (const float*)d_in[1];
    const float* w1       = (const float*)d_in[2];
    const float* b1       = (const float*)d_in[3];
    const float* w2       = (const float*)d_in[4];
    const float* b2       = (const float*)d_in[5];
    const float* fd_w     = (const float*)d_in[6];
    const float* fd_b     = (const float*)d_in[7];
    const float* fd_scale = (const float*)d_in[8];
    const float* fd_bias  = (const float*)d_in[9];
    const float* fd_mean  = (const float*)d_in[10];
    const float* fd_var   = (const float*)d_in[11];
    const float* fu_w     = (const float*)d_in[12];
    const float* fu_b     = (const float*)d_in[13];
    const float* fu_scale = (const float*)d_in[14];
    const float* fu_bias  = (const float*)d_in[15];
    const float* fu_mean  = (const float*)d_in[16];
    const float* fu_var   = (const float*)d_in[17];

    float* ws = (float*)d_ws;
    float* part = (float*)((char*)d_ws + WS_PART_BYTE);
    unsigned int* depthT = (unsigned int*)((char*)d_ws + WS_DEPTHT_BYTE);
    unsigned int* rgbT   = (unsigned int*)((char*)d_ws + WS_RGBT_BYTE);
    float* out = (float*)d_out;

    k_consts<<<1, 64, 0, stream>>>(fd_scale, fd_bias, fd_mean, fd_var, fd_b,
                                   fu_scale, fu_bias, fu_mean, fu_var, fu_b, ws);
    k_nhwc<<<dim3(65, 64), 256, 0, stream>>>(rgb, depth, rgbT, depthT, part);
    k_poolhid<<<CB, 256, 0, stream>>>(part, w1, b1, ws);
    k_kernwk<<<CB, 256, 0, stream>>>(w2, b2, ws);
    k_effw<<<CB, 256, 0, stream>>>(fu_w, ws);
    k_prepw<<<304, 256, 0, stream>>>(fd_w, ws);

    dim3 grid(WW / 32, HH / 8, CB);
    k_fused<<<grid, 256, 0, stream>>>((const unsigned short*)rgbT,
                                      (const unsigned short*)depthT, ws, out);
}

// Round 18
// 405.643 us; speedup vs baseline: 1.0482x; 1.0482x over previous
//
#include <hip/hip_runtime.h>
#include <hip/hip_bf16.h>

#define CB 64      // B == C == 64
#define HH 128
#define WW 128
#define KK 4
#define EPSV 1e-5f
#define HWSZ (HH*WW)

using f32x4   = __attribute__((ext_vector_type(4))) float;
using f32x16  = __attribute__((ext_vector_type(16))) float;
using short8  = __attribute__((ext_vector_type(8))) short;

// ---- workspace layout ----
static constexpr size_t WS_POOLED = 0;          // [64][128] (unused after fusion; kept)
static constexpr size_t WS_HID    = 8192;       // [64][64]
static constexpr size_t WS_KERN   = 12288;      // [64][2304] byte range reused by bf16 weights
static constexpr size_t WS_SSQ    = 159744;     // [64][4] (unused after fusion; kept)
static constexpr size_t WS_WK     = 160000;     // [64][576]
static constexpr size_t WS_EFFW   = 196864;     // [64][576]
static constexpr size_t WS_FUW2   = 233728;     // [64][64]
static constexpr size_t WS_FDINV  = 237824;     // [64]
static constexpr size_t WS_FDBETA = 237888;     // [64]
static constexpr size_t WS_FUINV  = 237952;     // [64]
static constexpr size_t WS_FUBETA = 238016;     // [64]
// byte offsets inside dead WS_KERN byte range (49152..638976):
// lane-coalesced weight layout: [tap][Kq][oh][lane 0..63][8 bf16]
static constexpr size_t WT3_BYTE = 49152;              // bf16 36864 = 73728 B
static constexpr size_t WFD_BYTE = 49152 + 73728;      // bf16 36864
static constexpr size_t W1_BYTE  = 49152 + 147456;     // bf16 [Kq][oh][lane][8] = 4096
// big buffers:
static constexpr size_t WS_PART_BYTE   = 4u << 20;     // f32 [64][64 ypairs][128]
static constexpr size_t WS_DEPTHT_BYTE = 8u << 20;     // bf16 [64][130][130][64] zero-padded
static constexpr size_t WS_RGBT_BYTE   = 140u << 20;   // bf16 [64][130][130][64] zero-padded

// ---------------- small kernels ----------------

__global__ void k_consts(const float* __restrict__ fd_scale, const float* __restrict__ fd_bias,
                         const float* __restrict__ fd_mean, const float* __restrict__ fd_var,
                         const float* __restrict__ fd_b,
                         const float* __restrict__ fu_scale, const float* __restrict__ fu_bias,
                         const float* __restrict__ fu_mean, const float* __restrict__ fu_var,
                         const float* __restrict__ fu_b,
                         float* __restrict__ ws) {
    int c = threadIdx.x;
    if (c < CB) {
        float fdi = fd_scale[c] / sqrtf(fd_var[c] + EPSV);
        ws[WS_FDINV + c]  = fdi;
        ws[WS_FDBETA + c] = (fd_b[c] - fd_mean[c]) * fdi + fd_bias[c];
        float fui = fu_scale[c] / sqrtf(fu_var[c] + EPSV);
        ws[WS_FUINV + c]  = fui;
        ws[WS_FUBETA + c] = (fu_b[c] - fu_mean[c]) * fui + fu_bias[c];
    }
}

__device__ __forceinline__ unsigned int pack_bf16(float a, float b) {
    __hip_bfloat16 ha = __float2bfloat16(a), hb = __float2bfloat16(b);
    return (unsigned int)*(unsigned short*)&ha | ((unsigned int)*(unsigned short*)&hb << 16);
}

// NCHW f32 -> padded NHWC bf16 transpose + pool partials (round-13, verified ~175 us).
__global__ __launch_bounds__(256) void k_nhwc(const float* __restrict__ rgb,
                                              const float* __restrict__ depth,
                                              unsigned int* __restrict__ rgbT,
                                              unsigned int* __restrict__ depthT,
                                              float* __restrict__ part) {
    int g = blockIdx.x;    // 0..63 row-pairs; 64 = border-rows block
    int b = blockIdx.y;
    int t = threadIdx.x;

    if (g == 64) {         // zero padded rows yp=0,129 for both tensors
        unsigned int* dR0 = rgbT   + ((size_t)b * 130 + 0)   * 130 * 32;
        unsigned int* dR1 = rgbT   + ((size_t)b * 130 + 129) * 130 * 32;
        unsigned int* dD0 = depthT + ((size_t)b * 130 + 0)   * 130 * 32;
        unsigned int* dD1 = depthT + ((size_t)b * 130 + 129) * 130 * 32;
        for (int i = t; i < 130 * 32; i += 256) {
            dR0[i] = 0u; dR1[i] = 0u; dD0[i] = 0u; dD1[i] = 0u;
        }
        return;
    }
    int y0 = g * 2;
    {   // side borders x'=0,129 for padded rows y0+1, y0+2 (both tensors)
        int tensor = t >> 7, side = (t >> 6) & 1, row = (t >> 5) & 1, j = t & 31;
        unsigned int* d = tensor ? depthT : rgbT;
        d[(((size_t)b * 130 + (y0 + 1 + row)) * 130 + (side ? 129 : 0)) * 32 + j] = 0u;
    }

    __shared__ unsigned int staged[32][260];   // [ch-pair][px 0..255], padded
    __shared__ float poolacc[128];
    int w = t >> 6, lane = t & 63;

    #pragma unroll
    for (int ph = 0; ph < 2; ++ph) {
        const float* src = ph ? depth : rgb;
        unsigned int* dst = ph ? depthT : rgbT;
        if (ph) __syncthreads();            // staged reuse barrier

        #pragma unroll
        for (int i = 0; i < 8; ++i) {
            int pair = i * 4 + w;           // wave-uniform
            int c = pair * 2;
            const float4* s0 = (const float4*)(src + ((size_t)(b * CB + c)) * HWSZ
                                               + (size_t)y0 * WW);
            const float4* s1 = (const float4*)(src + ((size_t)(b * CB + c + 1)) * HWSZ
                                               + (size_t)y0 * WW);
            float4 v0 = s0[lane];
            float4 v1 = s1[lane];
            unsigned int pk0 = pack_bf16(v0.x, v1.x);
            unsigned int pk1 = pack_bf16(v0.y, v1.y);
            unsigned int pk2 = pack_bf16(v0.z, v1.z);
            unsigned int pk3 = pack_bf16(v0.w, v1.w);
            uint4 q = {pk0, pk1, pk2, pk3};
            *(uint4*)&staged[pair][lane * 4] = q;
            float sa = v0.x + v0.y + v0.z + v0.w;
            float sb = v1.x + v1.y + v1.z + v1.w;
            #pragma unroll
            for (int off = 32; off; off >>= 1) {
                sa += __shfl_down(sa, off, 64);
                sb += __shfl_down(sb, off, 64);
            }
            if (lane == 0) {
                poolacc[ph * 64 + c]     = sa;
                poolacc[ph * 64 + c + 1] = sb;
            }
        }
        __syncthreads();

        {   // write: thread t -> pixel t, FULL 128B NHWC line
            int row = t >> 7, x = t & 127;
            unsigned int line[32];
            #pragma unroll
            for (int p = 0; p < 32; ++p) line[p] = staged[p][t];
            unsigned int* dp = dst + (((size_t)b * 130 + (y0 + 1 + row)) * 130 + 1 + x) * 32;
            #pragma unroll
            for (int q = 0; q < 8; ++q)
                *(uint4*)(dp + q * 4) = *(uint4*)&line[q * 4];
        }
    }
    __syncthreads();
    if (t < 128)
        part[((size_t)b * 64 + g) * 128 + t] = poolacc[t];
}

// fused pool-finish + hidden MLP (round-17, verified)
__global__ __launch_bounds__(256) void k_poolhid(const float* __restrict__ part,
                                                 const float* __restrict__ w1,
                                                 const float* __restrict__ b1,
                                                 float* __restrict__ ws) {
    int b = blockIdx.x, t = threadIdx.x, cc = t & 127, q = t >> 7;
    float s = 0.f;
    for (int g = q * 32; g < q * 32 + 32; ++g)
        s += part[((size_t)b * 64 + g) * 128 + cc];
    __shared__ float red[2][128];
    __shared__ float p[128];
    red[q][cc] = s;
    __syncthreads();
    if (t < 128) p[t] = (red[0][t] + red[1][t]) * (1.f / 16384.f);
    __syncthreads();
    if (t < CB) {
        float s2 = b1[t];
        const float* wr = w1 + t * 128;
        #pragma unroll 8
        for (int i = 0; i < 128; ++i) s2 += p[i] * wr[i];
        ws[WS_HID + b * CB + t] = fmaxf(s2, 0.f);
    }
}

// fused kernel-gen + softmax + weighted-kernel (round-17, verified)
__global__ __launch_bounds__(256) void k_kernwk(const float* __restrict__ w2,
                                                const float* __restrict__ b2,
                                                float* __restrict__ ws) {
    __shared__ float h[CB];
    __shared__ float kernL[2304];
    __shared__ float attn[KK];
    __shared__ float ssq[KK];
    int b = blockIdx.x, t = threadIdx.x;
    if (t < CB) h[t] = ws[WS_HID + b * CB + t];
    __syncthreads();
    float local = 0.f;
    #pragma unroll
    for (int r9 = 0; r9 < 9; ++r9) {
        int r = t * 9 + r9;
        float s = b2[r];
        const float* wr = w2 + r * CB;
        #pragma unroll 8
        for (int m = 0; m < CB; ++m) s += h[m] * wr[m];
        kernL[r] = s;
        local += s * s;
    }
    #pragma unroll
    for (int off = 32; off; off >>= 1) local += __shfl_down(local, off, 64);
    if ((t & 63) == 0) ssq[t >> 6] = local;
    __syncthreads();
    if (t == 0) {
        float n[KK], m = -1e30f;
        #pragma unroll
        for (int k = 0; k < KK; ++k) { n[k] = sqrtf(ssq[k]); m = fmaxf(m, n[k]); }
        float e[KK], den = 0.f;
        #pragma unroll
        for (int k = 0; k < KK; ++k) { e[k] = expf(n[k] - m); den += e[k]; }
        float inv = 1.f / den;
        #pragma unroll
        for (int k = 0; k < KK; ++k) attn[k] = e[k] * inv;
    }
    __syncthreads();
    float a0 = attn[0], a1 = attn[1], a2 = attn[2], a3 = attn[3];
    for (int idx = t; idx < 576; idx += 256) {
        float s = a0 * kernL[idx] + a1 * kernL[576 + idx]
                + a2 * kernL[1152 + idx] + a3 * kernL[1728 + idx];
        ws[WS_WK + b * 576 + idx] = s;
    }
}

__global__ __launch_bounds__(256) void k_effw(const float* __restrict__ fu_w, float* __restrict__ ws) {
    int o = blockIdx.x, t = threadIdx.x;
    __shared__ float fw[CB];
    float fi = ws[WS_FUINV + o];
    if (t < CB) {
        fw[t] = fu_w[o * 128 + t] * fi;
        ws[WS_FUW2 + o * CB + t] = fu_w[o * 128 + CB + t] * fi;
    }
    __syncthreads();
    for (int idx = t; idx < 576; idx += 256) {
        float s = 0.f;
        #pragma unroll 8
        for (int c = 0; c < CB; ++c) s += fw[c] * ws[WS_WK + c * 576 + idx];
        ws[WS_EFFW + o * 576 + idx] = s;
    }
}

// lane-coalesced A-frag layouts for mfma_32x32x16:
//   wt[(((tap*4+Kq)*2+oh)*64 + lane)*8 + j] = W[och = oh*32+(lane&31)][cin = Kq*16+(lane>>5)*8+j]
__global__ void k_prepw(const float* __restrict__ fd_w, float* __restrict__ ws) {
    int e = blockIdx.x * 256 + threadIdx.x;
    unsigned short* wt3 = (unsigned short*)((char*)ws + WT3_BYTE);
    unsigned short* wfd = (unsigned short*)((char*)ws + WFD_BYTE);
    unsigned short* w1o = (unsigned short*)((char*)ws + W1_BYTE);
    if (e < 73728) {
        int set = (e >= 36864) ? 1 : 0;
        int e2 = set ? e - 36864 : e;
        int j = e2 & 7, l = (e2 >> 3) & 63, oh = (e2 >> 9) & 1, Kq = (e2 >> 10) & 3, tap = e2 >> 12;
        int och = oh * 32 + (l & 31);
        int cin = Kq * 16 + (l >> 5) * 8 + j;
        float v = set ? fd_w[(och * 64 + cin) * 9 + tap] * ws[WS_FDINV + och]
                      : ws[WS_EFFW + och * 576 + cin * 9 + tap];
        __hip_bfloat16 h = __float2bfloat16(v);
        (set ? wfd : wt3)[e2] = *(unsigned short*)&h;
    } else if (e < 77824) {
        int e3 = e - 73728;
        int j = e3 & 7, l = (e3 >> 3) & 63, oh = (e3 >> 9) & 1, Kq = e3 >> 10;
        int och = oh * 32 + (l & 31);
        int cin = Kq * 16 + (l >> 5) * 8 + j;
        __hip_bfloat16 h = __float2bfloat16(ws[WS_FUW2 + och * CB + cin]);
        w1o[e3] = *(unsigned short*)&h;
    }
}

// ---------------- fused conv kernel (round-16 version, verified 213 us) -------
// Tile 32x8 px. Input LDS: [10 rows][34 x][8 chunks of 8 bf16] = 43520 B,
// linear dest, XOR swizzle (cs ^ (xx&7)) on global source + ds_read side.
// Wave w owns ALL 64 out-channels for rows {2w, 2w+1}. Each B-frag ds_read
// feeds TWO 32x32x16 MFMAs. (256,2): no spill (WRITE = 262144 KB exact).
// Tap-pipelined weight loads (double-buffered wa[2][2][4], compile-time idx).

__device__ __forceinline__ void gload_lds16(const void* g, void* l) {
    __builtin_amdgcn_global_load_lds((const __attribute__((address_space(1))) unsigned int*)g,
                                     (__attribute__((address_space(3))) unsigned int*)l, 16, 0, 0);
}

__device__ __forceinline__ void stage_async(const unsigned short* __restrict__ T, int b,
                                            int y0p, int x0p, int t, char* tile) {
    const char* base = (const char*)(T + (((size_t)b * 130 + y0p) * 130 + x0p) * 64);
    #pragma unroll
    for (int it = 0; it < 10; ++it) {
        int n = it * 256 + t;
        int row = n / 272, rem = n - row * 272;
        int xx = rem >> 3, cs = rem & 7;
        gload_lds16(base + (size_t)row * 16640 + xx * 128 + ((cs ^ (xx & 7)) << 4),
                    tile + n * 16);
    }
    if (t < 160) {
        int n = 2560 + t;
        int row = n / 272, rem = n - row * 272;
        int xx = rem >> 3, cs = rem & 7;
        gload_lds16(base + (size_t)row * 16640 + xx * 128 + ((cs ^ (xx & 7)) << 4),
                    tile + n * 16);
    }
}

__device__ __forceinline__ void load_tap(short8 (&dst)[2][4], const unsigned short* __restrict__ Wt,
                                         int tap, int lane) {
    #pragma unroll
    for (int Kq = 0; Kq < 4; ++Kq)
        #pragma unroll
        for (int oh = 0; oh < 2; ++oh)
            dst[oh][Kq] = *(const short8*)(Wt + ((((tap * 4 + Kq) * 2 + oh) * 64 + lane) << 3));
}

__device__ __forceinline__ void conv3x3w2(f32x16 (&acc)[2][2], const unsigned short* __restrict__ Wt,
                                          const char* tile, int w, int lane) {
    int px = lane & 31, hi = lane >> 5;
    short8 wa[2][2][4];                 // [buf][oh][Kq], buf = tap&1 (compile-time)
    load_tap(wa[0], Wt, 0, lane);
    #pragma unroll
    for (int tap = 0; tap < 9; ++tap) {
        const int cur = tap & 1;
        if (tap < 8) load_tap(wa[cur ^ 1], Wt, tap + 1, lane);   // prefetch next tap
        const int di = tap / 3, dj = tap % 3;
        const int xx = px + dj;
        #pragma unroll
        for (int pxg = 0; pxg < 2; ++pxg) {
            const char* base = tile + (w * 2 + pxg + di) * 4352 + xx * 128;
            #pragma unroll
            for (int Kq = 0; Kq < 4; ++Kq) {
                short8 bf = *(const short8*)(base + (((Kq * 2 + hi) ^ (xx & 7)) << 4));
                __builtin_amdgcn_s_setprio(1);
                acc[0][pxg] = __builtin_amdgcn_mfma_f32_32x32x16_bf16(wa[cur][0][Kq], bf, acc[0][pxg], 0, 0, 0);
                acc[1][pxg] = __builtin_amdgcn_mfma_f32_32x32x16_bf16(wa[cur][1][Kq], bf, acc[1][pxg], 0, 0, 0);
                __builtin_amdgcn_s_setprio(0);
            }
        }
    }
}

__global__ __launch_bounds__(256, 2) void k_fused(const unsigned short* __restrict__ rgbT,
                                                  const unsigned short* __restrict__ depthT,
                                                  const float* __restrict__ ws,
                                                  float* __restrict__ out) {
    __shared__ __align__(16) char tile[43520];
    int b = blockIdx.z;
    int x0 = blockIdx.x * 32, y0 = blockIdx.y * 8;
    int t = threadIdx.x, lane = t & 63, w = t >> 6;
    int px = lane & 31, hi = lane >> 5;

    const unsigned short* wfd = (const unsigned short*)((const char*)ws + WFD_BYTE);
    const unsigned short* wt3 = (const unsigned short*)((const char*)ws + WT3_BYTE);
    const unsigned short* w1o = (const unsigned short*)((const char*)ws + W1_BYTE);

    // ---- issue depth tile loads (async into LDS) ----
    stage_async(depthT, b, y0, x0, t, tile);

    // facc init = fd beta (C-layout: och = oh*32 + (r&3) + 8*(r>>2) + 4*hi)
    f32x16 facc[2][2];
    #pragma unroll
    for (int oh = 0; oh < 2; ++oh) {
        f32x16 bi;
        #pragma unroll
        for (int r = 0; r < 16; ++r)
            bi[r] = ws[WS_FDBETA + oh * 32 + (r & 3) + 8 * (r >> 2) + 4 * hi];
        facc[oh][0] = bi;
        facc[oh][1] = bi;
    }
    __syncthreads();   // depth tile resident

    conv3x3w2(facc, wfd, tile, w, lane);
    __syncthreads();   // depth-tile reads done; reuse tile[0..32768) as freq_lds

    // ---- freq -> LDS [px][ch] bf16, chunk-slot XOR by (px&7), ReLU ----
    {
        unsigned int* fl = (unsigned int*)tile;
        #pragma unroll
        for (int oh = 0; oh < 2; ++oh)
            #pragma unroll
            for (int pxg = 0; pxg < 2; ++pxg) {
                int p = (w * 2 + pxg) * 32 + px;
                #pragma unroll
                for (int q = 0; q < 4; ++q) {
                    unsigned int u0 = pack_bf16(fmaxf(facc[oh][pxg][q * 4 + 0], 0.f),
                                                fmaxf(facc[oh][pxg][q * 4 + 1], 0.f));
                    unsigned int u1 = pack_bf16(fmaxf(facc[oh][pxg][q * 4 + 2], 0.f),
                                                fmaxf(facc[oh][pxg][q * 4 + 3], 0.f));
                    int slot = (q + oh * 4) ^ (p & 7);
                    int dw = p * 32 + slot * 4 + hi * 2;
                    fl[dw] = u0;
                    fl[dw + 1] = u1;
                }
            }
    }
    __syncthreads();   // freq_lds visible

    // ---- acc init + 1x1 over freq ----
    f32x16 acc[2][2];
    #pragma unroll
    for (int oh = 0; oh < 2; ++oh) {
        f32x16 bi;
        #pragma unroll
        for (int r = 0; r < 16; ++r)
            bi[r] = ws[WS_FUBETA + oh * 32 + (r & 3) + 8 * (r >> 2) + 4 * hi];
        acc[oh][0] = bi;
        acc[oh][1] = bi;
    }
    #pragma unroll
    for (int Kq = 0; Kq < 4; ++Kq) {
        short8 w1a[2];
        #pragma unroll
        for (int oh = 0; oh < 2; ++oh)
            w1a[oh] = *(const short8*)(w1o + (((Kq * 2 + oh) * 64 + lane) << 3));
        #pragma unroll
        for (int pxg = 0; pxg < 2; ++pxg) {
            int p = (w * 2 + pxg) * 32 + px;
            short8 bf = *(const short8*)(tile + p * 128 + (((Kq * 2 + hi) ^ (p & 7)) << 4));
            __builtin_amdgcn_s_setprio(1);
            acc[0][pxg] = __builtin_amdgcn_mfma_f32_32x32x16_bf16(w1a[0], bf, acc[0][pxg], 0, 0, 0);
            acc[1][pxg] = __builtin_amdgcn_mfma_f32_32x32x16_bf16(w1a[1], bf, acc[1][pxg], 0, 0, 0);
            __builtin_amdgcn_s_setprio(0);
        }
    }
    __syncthreads();   // freq_lds reads done

    // ---- issue rgb tile loads ----
    stage_async(rgbT, b, y0, x0, t, tile);
    __syncthreads();   // rgb tile resident

    conv3x3w2(acc, wt3, tile, w, lane);
    __syncthreads();   // tile reads done; reuse as transpose slab

    // ---- epilogue: per-wave 64x33 slab transpose -> full-128B-line stores ----
    float* slab = (float*)(tile + w * 8704);
    #pragma unroll
    for (int pxg = 0; pxg < 2; ++pxg) {
        #pragma unroll
        for (int oh = 0; oh < 2; ++oh)
            #pragma unroll
            for (int q = 0; q < 4; ++q)
                #pragma unroll
                for (int i = 0; i < 4; ++i)
                    slab[(oh * 32 + q * 8 + hi * 4 + i) * 33 + px] =
                        fmaxf(acc[oh][pxg][q * 4 + i], 0.f);
        int y = y0 + w * 2 + pxg;
        #pragma unroll
        for (int c2 = 0; c2 < 32; ++c2) {
            int c = c2 * 2 + hi;
            out[(size_t)(b * CB + c) * HWSZ + (size_t)y * WW + x0 + px] = slab[c * 33 + px];
        }
    }
}

// ---------------- launch ----------------

extern "C" void kernel_launch(void* const* d_in, const int* in_sizes, int n_in,
                              void* d_out, int out_size, void* d_ws, size_t ws_size,
                              hipStream_t stream) {
    const float* rgb      = (const float*)d_in[0];
    const float* depth    = (const float*)d_in[1];
    const float* w1       = (const float*)d_in[2];
    const float* b1       = (const float*)d_in[3];
    const float* w2       = (const float*)d_in[4];
    const float* b2       = (const float*)d_in[5];
    const float* fd_w     = (const float*)d_in[6];
    const float* fd_b     = (const float*)d_in[7];
    const float* fd_scale = (const float*)d_in[8];
    const float* fd_bias  = (const float*)d_in[9];
    const float* fd_mean  = (const float*)d_in[10];
    const float* fd_var   = (const float*)d_in[11];
    const float* fu_w     = (const float*)d_in[12];
    const float* fu_b     = (const float*)d_in[13];
    const float* fu_scale = (const float*)d_in[14];
    const float* fu_bias  = (const float*)d_in[15];
    const float* fu_mean  = (const float*)d_in[16];
    const float* fu_var   = (const float*)d_in[17];

    float* ws = (float*)d_ws;
    float* part = (float*)((char*)d_ws + WS_PART_BYTE);
    unsigned int* depthT = (unsigned int*)((char*)d_ws + WS_DEPTHT_BYTE);
    unsigned int* rgbT   = (unsigned int*)((char*)d_ws + WS_RGBT_BYTE);
    float* out = (float*)d_out;

    k_consts<<<1, 64, 0, stream>>>(fd_scale, fd_bias, fd_mean, fd_var, fd_b,
                                   fu_scale, fu_bias, fu_mean, fu_var, fu_b, ws);
    k_nhwc<<<dim3(65, 64), 256, 0, stream>>>(rgb, depth, rgbT, depthT, part);
    k_poolhid<<<CB, 256, 0, stream>>>(part, w1, b1, ws);
    k_kernwk<<<CB, 256, 0, stream>>>(w2, b2, ws);
    k_effw<<<CB, 256, 0, stream>>>(fu_w, ws);
    k_prepw<<<304, 256, 0, stream>>>(fd_w, ws);

    dim3 grid(WW / 32, HH / 8, CB);
    k_fused<<<grid, 256, 0, stream>>>((const unsigned short*)rgbT,
                                      (const unsigned short*)depthT, ws, out);
}